// Round 12
// baseline (399.355 us; speedup 1.0000x reference)
//
#include <hip/hip_runtime.h>
#include <hip/hip_bf16.h>
#include <math.h>

#define N_PTS 20000
#define C_IN 128
#define C_OUT 64
#define M_PTS (N_PTS*8)
#define EPS 1e-5f

typedef __attribute__((ext_vector_type(8))) short short8;
typedef __attribute__((ext_vector_type(4))) float float4v;

__device__ __forceinline__ ushort f2bf(float f){
    unsigned int i = __float_as_uint(f);
    unsigned int r = i + 0x7fffu + ((i >> 16) & 1u);
    return (ushort)(r >> 16);
}
__device__ __forceinline__ float bf2f(ushort u){ return __uint_as_float(((unsigned int)u) << 16); }
__device__ __forceinline__ float silu(float z){ return z / (1.f + expf(-z)); }
// compact every-3rd-bit (15-bit morton) -> 5-bit coord
__device__ __forceinline__ int cmp5(int v){
    v &= 0x1249; v = (v | (v >> 2)) & 0x10C3; v = (v | (v >> 4)) & 0x100F; v = (v | (v >> 8)) & 0x1F;
    return v;
}

// stats layout (fp32, ws): [0..31] gn1 group sum, [32..63] gn1 group sumsq,
//                          [64..127] gn2 ch sum, [128..191] gn2 ch sumsq

// ================= K1: W1eff + wprep2 + pg_init(+zero rows) + gn1_partial =================
// blocks: [0,2048) W1eff, [2048,2480) Wt2, [2480,2608) pg_init, [2608,3120) gn1
__global__ void __launch_bounds__(256) prep_kernel(
    const float* __restrict__ W1, const float* __restrict__ W2,
    ushort* __restrict__ Wt1, ushort* __restrict__ Wt2,
    int* __restrict__ pg, ushort* __restrict__ h, ushort* __restrict__ h2,
    const float* __restrict__ x, float* __restrict__ stats)
{
    const int b = blockIdx.x, tid = threadIdx.x;
    if (b < 2048){
        // Wt1eff fragment order: idx = (((t*4+kb)*4+nb)*64+l)*8+j, t = o*8+jj in [0,64)
        int idx = b * 256 + tid;
        int j = idx & 7, l = (idx >> 3) & 63, nb = (idx >> 9) & 3, kb = (idx >> 11) & 3, t = idx >> 13;
        int ci = kb * 32 + (l >> 4) * 8 + j, co = nb * 16 + (l & 15);
        int o = t >> 3, jj = t & 7;
        int ox = (o >> 2) & 1, oy = (o >> 1) & 1, oz = o & 1;
        int jx = (jj >> 2) & 1, jy = (jj >> 1) & 1, jz = jj & 1;
        float s = 0.f;
#pragma unroll
        for (int dx = -1; dx <= 1; dx++){
            if (((ox + dx) >> 1) != ox + jx - 1) continue;
#pragma unroll
            for (int dy = -1; dy <= 1; dy++){
                if (((oy + dy) >> 1) != oy + jy - 1) continue;
#pragma unroll
                for (int dz = -1; dz <= 1; dz++){
                    if (((oz + dz) >> 1) != oz + jz - 1) continue;
                    s += W1[((dx+1)*9 + (dy+1)*3 + (dz+1)) * (C_IN*64) + ci * 64 + co];
                }
            }
        }
        Wt1[idx] = f2bf(s);
    } else if (b < 2480){
        // Wt2 fragment order: idx = (((t*2+kb)*4+nb)*64+l)*8+j, KB=2, t in [0,27)
        int idx = (b - 2048) * 256 + tid;
        int j = idx & 7, l = (idx >> 3) & 63, nb = (idx >> 9) & 3, kb = (idx >> 11) & 1, t = idx >> 12;
        int ci = kb * 32 + (l >> 4) * 8 + j, co = nb * 16 + (l & 15);
        Wt2[idx] = f2bf(W2[(t * C_OUT + ci) * 64 + co]);
    } else if (b < 2608){
        int i = (b - 2480) * 256 + tid;
        pg[i] = -1;
        if (b == 2480){
            if (tid < C_IN) h[(size_t)N_PTS * C_IN + tid] = 0;    // zero parent row
            if (tid < 256){                                        // 8 zero child rows (conv2)
                h2[(size_t)M_PTS * C_OUT + tid] = 0;
                h2[(size_t)M_PTS * C_OUT + 256 + tid] = 0;
            }
        }
    } else {
        // gn1 partial: 512 blocks, grid-stride rows, LDS + global atomics
        __shared__ float ls[64];
        if (tid < 64) ls[tid] = 0.f;
        __syncthreads();
        const int g = tid & 31;
        const int r0 = (b - 2608) * 8 + (tid >> 5);
        float sum = 0.f, sq = 0.f;
        for (int r = r0; r < N_PTS; r += 4096){
            float4 v = *(const float4*)(x + (size_t)r * C_IN + g * 4);
            sum += v.x + v.y + v.z + v.w;
            sq  += v.x*v.x + v.y*v.y + v.z*v.z + v.w*v.w;
        }
        atomicAdd(&ls[g], sum);
        atomicAdd(&ls[32 + g], sq);
        __syncthreads();
        if (tid < 64) atomicAdd(&stats[tid], ls[tid]);
    }
}

// ================= scatter: pg[cell] = parent index =================
__global__ void __launch_bounds__(256) scatter_kernel(
    const int* __restrict__ cds, int* __restrict__ pg)
{
    int i = blockIdx.x * 256 + threadIdx.x;
    if (i < N_PTS){
        const int* cd = cds + i * 4;
        pg[(cd[1] * 32 + cd[2]) * 32 + cd[3]] = i;
    }
}

// ================= 3-phase Morton sort =================
// Virtual thread t in [0,1024) owns morton cells [t*32, t*32+32).
__global__ void __launch_bounds__(64) sortA_kernel(
    const int* __restrict__ pg, int* __restrict__ cnt)
{
    int t = blockIdx.x * 64 + threadIdx.x;
    int c = 0;
    for (int i = 0; i < 32; i++){
        int m = t * 32 + i;
        int x = cmp5(m >> 2), y = cmp5(m >> 1), z = cmp5(m);
        c += (pg[(x * 32 + y) * 32 + z] >= 0) ? 1 : 0;
    }
    cnt[t] = c;
}
__global__ void __launch_bounds__(1024) sortB_kernel(
    const int* __restrict__ cnt, int* __restrict__ base)
{
    __shared__ int ps[1024];
    const int t = threadIdx.x;
    int c = cnt[t];
    ps[t] = c;
    __syncthreads();
    for (int off = 1; off < 1024; off <<= 1){
        int v = (t >= off) ? ps[t - off] : 0;
        __syncthreads();
        ps[t] += v;
        __syncthreads();
    }
    base[t] = ps[t] - c;   // exclusive prefix
}
__global__ void __launch_bounds__(64) sortC_kernel(
    int* __restrict__ pg, unsigned int* __restrict__ ordp,
    const int* __restrict__ base)
{
    int t = blockIdx.x * 64 + threadIdx.x;
    int run = base[t];
    for (int i = 0; i < 32; i++){
        int m = t * 32 + i;
        int x = cmp5(m >> 2), y = cmp5(m >> 1), z = cmp5(m);
        int ci = (x * 32 + y) * 32 + z;
        int pi = pg[ci];
        if (pi >= 0){
            ordp[run] = ((unsigned int)pi << 15) | (unsigned int)((x << 10) | (y << 5) | z);
            pg[ci] = run;
            run++;
        }
    }
}

// ================= K2: h_compute (rank-ordered) + skip (rank-ordered) =================
__global__ void __launch_bounds__(256) mid_kernel(
    const int* __restrict__ cds, const int* __restrict__ pg,
    const float* __restrict__ x, const float* __restrict__ stats,
    const float* __restrict__ g1, const float* __restrict__ b1, ushort* __restrict__ h,
    const float* __restrict__ Wsk, const float* __restrict__ bsk, float* __restrict__ s)
{
    __shared__ float w[C_IN * C_OUT];
    const int b = blockIdx.x, tid = threadIdx.x;
    if (b < 2500){
        int i = (b * 256 + tid) * 4;              // i < 2,560,000 exactly
        int row = i >> 7, c0 = i & 127;           // c0 multiple of 4 -> one group
        const int* cd = cds + row * 4;
        int rk = pg[(cd[1] * 32 + cd[2]) * 32 + cd[3]];
        int g = c0 >> 2;
        float mu = stats[g] * (1.0f / (N_PTS * 4.0f));
        float var = stats[32 + g] * (1.0f / (N_PTS * 4.0f)) - mu * mu;
        float rs = rsqrtf(var + EPS);
        float4 v = *(const float4*)(x + i);
        ushort4 o;
        o.x = f2bf(silu((v.x - mu) * rs * g1[c0+0] + b1[c0+0]));
        o.y = f2bf(silu((v.y - mu) * rs * g1[c0+1] + b1[c0+1]));
        o.z = f2bf(silu((v.z - mu) * rs * g1[c0+2] + b1[c0+2]));
        o.w = f2bf(silu((v.w - mu) * rs * g1[c0+3] + b1[c0+3]));
        *(ushort4*)(h + (size_t)rk * C_IN + c0) = o;
    } else {
        for (int j = tid; j < C_IN * C_OUT; j += 256) w[j] = Wsk[j];
        __syncthreads();
        int co = tid & 63, pr = tid >> 6;
        int p = (b - 2500) * 4 + pr;
        const int* cd = cds + p * 4;
        int rk = pg[(cd[1] * 32 + cd[2]) * 32 + cd[3]];
        const float* xr = x + (size_t)p * C_IN;
        float a = bsk[co];
        for (int cb = 0; cb < C_IN; cb += 4){
            float4 v = *(const float4*)(xr + cb);
            a += v.x * w[(cb+0)*64+co] + v.y * w[(cb+1)*64+co]
               + v.z * w[(cb+2)*64+co] + v.w * w[(cb+3)*64+co];
        }
        s[(size_t)rk * C_OUT + co] = a;
    }
}

// ================= conv1: halo-staged corner GEMM =================
// Tile = 64-cell Morton box (4x4x4 parents space) -> contiguous rank interval
// [base[2t], base[2t+2]) of <=64 parents (one M-pass). The 6x6x6 halo box
// (216 cells, ~130 rows x 256B) is staged into LDS in ONE parallel epoch
// (2 threads/row); then 8 octant-waves run 8 corner taps reading A-frags from
// LDS (272B-padded rows, ~2-way conflicts) -- zero per-tap global gathers.
// Grid 512 XCD-chunked: xcd=b&7 owns tiles [xcd*64,(xcd+1)*64) -> halo overlap
// between adjacent tiles reuses in that XCD's L2. Fused GN2 sums.
#define HROWS 217              // 216 halo cells + 1 zero row
#define HPITCH 136             // ushorts per row (272B, +16B pad vs 256B)
__global__ void __launch_bounds__(512, 4) conv1_halo(
    const ushort* __restrict__ feat, const int* __restrict__ pg,
    const unsigned int* __restrict__ ordp, const int* __restrict__ base,
    const ushort* __restrict__ Wt, const float* __restrict__ bias,
    ushort* __restrict__ hf1_bf, float* __restrict__ statsAcc)
{
    __shared__ ushort hstage[HROWS * HPITCH];   // 59,024 B
    const int tid = threadIdx.x;
    const int b = blockIdx.x;
    const int t = (b & 7) * 64 + (b >> 3);
    const int pbase = base[2 * t];
    const int pend  = (t == 511) ? N_PTS : base[2 * t + 2];
    if (pbase >= pend) return;               // block-uniform, before barrier
    const int m0 = t << 6;
    const int hx0 = cmp5(m0 >> 2) - 1, hy0 = cmp5(m0 >> 1) - 1, hz0 = cmp5(m0) - 1;

    // stage: 2 threads per row
    {
        int r = tid >> 1, half = tid & 1;
        if (r < HROWS){
            uint4* dst = (uint4*)(hstage + r * HPITCH + half * 64);
            int rk = -1;
            if (r < 216){
                int lx = r / 36, ly = (r / 6) % 6, lz = r % 6;
                int cx = hx0 + lx, cy = hy0 + ly, cz = hz0 + lz;
                if ((unsigned)cx < 32u && (unsigned)cy < 32u && (unsigned)cz < 32u)
                    rk = pg[cx * 1024 + cy * 32 + cz];
            }
            if (rk >= 0){
                const uint4* src = (const uint4*)(feat + (size_t)rk * C_IN + half * 64);
#pragma unroll
                for (int i = 0; i < 8; i++) dst[i] = src[i];
            } else {
                uint4 zz; zz.x = zz.y = zz.z = zz.w = 0u;
#pragma unroll
                for (int i = 0; i < 8; i++) dst[i] = zz;
            }
        }
    }
    __syncthreads();

    const int o = tid >> 6, l = tid & 63;    // wave id == octant
    const int r16 = l & 15, qd = l >> 4;
    const int ox = (o >> 2) & 1, oy = (o >> 1) & 1, oz = o & 1;

    // lane's slot = pbase + l; LDS byte offsets of its 8 corner rows
    int rows8[8];
    {
        int valid = (pbase + l) < pend;
        int cell = (int)(ordp[valid ? (pbase + l) : pbase] & 0x7FFFu);
        int lx = ((cell >> 10) & 31) - hx0;
        int ly = ((cell >> 5) & 31) - hy0;
        int lz = (cell & 31) - hz0;
#pragma unroll
        for (int j = 0; j < 8; j++){
            int nx = lx + ox - 1 + ((j >> 2) & 1);
            int ny = ly + oy - 1 + ((j >> 1) & 1);
            int nz = lz + oz - 1 + (j & 1);
            int idx = (nx * 6 + ny) * 6 + nz;
            rows8[j] = (valid ? idx : 216) * (HPITCH * 2);   // byte offset
        }
    }

    float4v acc[16];
#pragma unroll
    for (int c = 0; c < 16; c++) acc[c] = 0.f;

#pragma unroll
    for (int j = 0; j < 8; j++){
        int fr0 = __shfl(rows8[j],      r16, 64);
        int fr1 = __shfl(rows8[j], 16 + r16, 64);
        int fr2 = __shfl(rows8[j], 32 + r16, 64);
        int fr3 = __shfl(rows8[j], 48 + r16, 64);
        const ushort* a0 = (const ushort*)((const char*)hstage + fr0) + qd * 8;
        const ushort* a1 = (const ushort*)((const char*)hstage + fr1) + qd * 8;
        const ushort* a2 = (const ushort*)((const char*)hstage + fr2) + qd * 8;
        const ushort* a3 = (const ushort*)((const char*)hstage + fr3) + qd * 8;
        const ushort* wt = Wt + (size_t)(o * 8 + j) * 8192 + l * 8;
#pragma unroll
        for (int kb = 0; kb < 4; kb++){
            short8 b0 = *(const short8*)(wt + (kb*4+0)*512);
            short8 b1 = *(const short8*)(wt + (kb*4+1)*512);
            short8 b2 = *(const short8*)(wt + (kb*4+2)*512);
            short8 b3 = *(const short8*)(wt + (kb*4+3)*512);
            short8 av0 = *(const short8*)(a0 + kb*32);
            short8 av1 = *(const short8*)(a1 + kb*32);
            short8 av2 = *(const short8*)(a2 + kb*32);
            short8 av3 = *(const short8*)(a3 + kb*32);
            acc[0]  = __builtin_amdgcn_mfma_f32_16x16x32_bf16(av0, b0, acc[0],  0, 0, 0);
            acc[1]  = __builtin_amdgcn_mfma_f32_16x16x32_bf16(av0, b1, acc[1],  0, 0, 0);
            acc[2]  = __builtin_amdgcn_mfma_f32_16x16x32_bf16(av0, b2, acc[2],  0, 0, 0);
            acc[3]  = __builtin_amdgcn_mfma_f32_16x16x32_bf16(av0, b3, acc[3],  0, 0, 0);
            acc[4]  = __builtin_amdgcn_mfma_f32_16x16x32_bf16(av1, b0, acc[4],  0, 0, 0);
            acc[5]  = __builtin_amdgcn_mfma_f32_16x16x32_bf16(av1, b1, acc[5],  0, 0, 0);
            acc[6]  = __builtin_amdgcn_mfma_f32_16x16x32_bf16(av1, b2, acc[6],  0, 0, 0);
            acc[7]  = __builtin_amdgcn_mfma_f32_16x16x32_bf16(av1, b3, acc[7],  0, 0, 0);
            acc[8]  = __builtin_amdgcn_mfma_f32_16x16x32_bf16(av2, b0, acc[8],  0, 0, 0);
            acc[9]  = __builtin_amdgcn_mfma_f32_16x16x32_bf16(av2, b1, acc[9],  0, 0, 0);
            acc[10] = __builtin_amdgcn_mfma_f32_16x16x32_bf16(av2, b2, acc[10], 0, 0, 0);
            acc[11] = __builtin_amdgcn_mfma_f32_16x16x32_bf16(av2, b3, acc[11], 0, 0, 0);
            acc[12] = __builtin_amdgcn_mfma_f32_16x16x32_bf16(av3, b0, acc[12], 0, 0, 0);
            acc[13] = __builtin_amdgcn_mfma_f32_16x16x32_bf16(av3, b1, acc[13], 0, 0, 0);
            acc[14] = __builtin_amdgcn_mfma_f32_16x16x32_bf16(av3, b2, acc[14], 0, 0, 0);
            acc[15] = __builtin_amdgcn_mfma_f32_16x16x32_bf16(av3, b3, acc[15], 0, 0, 0);
        }
    }

    // epilogue: C/D col = lane&15, row = (lane>>4)*4 + reg; row-in-tile = pbase+sl
    float bsv[4] = { bias[r16], bias[16 + r16], bias[32 + r16], bias[48 + r16] };
    float ps[4] = {0,0,0,0}, pq[4] = {0,0,0,0};
#pragma unroll
    for (int rb = 0; rb < 4; rb++)
#pragma unroll
        for (int nb = 0; nb < 4; nb++)
#pragma unroll
            for (int rg = 0; rg < 4; rg++){
                int sl = rb * 16 + qd * 4 + rg;
                int pr = pbase + sl;
                float v = acc[rb * 4 + nb][rg] + bsv[nb];
                if (pr < pend){
                    hf1_bf[(size_t)(pr * 8 + o) * 64 + nb * 16 + r16] = f2bf(v);
                    ps[nb] += v; pq[nb] += v * v;
                }
            }
#pragma unroll
    for (int nb = 0; nb < 4; nb++){
        float s1 = ps[nb], s2 = pq[nb];
        s1 += __shfl_xor(s1, 16, 64); s2 += __shfl_xor(s2, 16, 64);
        s1 += __shfl_xor(s1, 32, 64); s2 += __shfl_xor(s2, 32, 64);
        if (qd == 0){
            atomicAdd(&statsAcc[64 + nb * 16 + r16], s1);
            atomicAdd(&statsAcc[128 + nb * 16 + r16], s2);
        }
    }
}

// ================= conv2: corner-based implicit GEMM, sorted tiles, 4-octant blocks =================
// (round-10-verified form: direct writes, no prefetch, grid 626.)
__global__ void __launch_bounds__(256, 4) conv2_corner(
    const ushort* __restrict__ feat, const int* __restrict__ pg,
    const unsigned int* __restrict__ ordp,
    const ushort* __restrict__ Wt, const float* __restrict__ bias,
    const float* __restrict__ skip, float* __restrict__ out)
{
    const int tid = threadIdx.x;
    const int wid = tid >> 6, l = tid & 63;
    const int r16 = l & 15, qd = l >> 4;
    const int b = blockIdx.x;
    const int tile = b >> 1;
    const int o = (b & 1) * 4 + wid;
    const int ox = (o >> 2) & 1, oy = (o >> 1) & 1, oz = o & 1;
    const int mb = tile * 64;

    int slot = mb + l;
    int cs = slot < N_PTS ? slot : N_PTS - 1;
    unsigned int op = ordp[cs];
    int sp = (int)(op >> 15);                // original parent index (for out rows)
    int cell = (int)(op & 0x7FFFu);
    int px = (cell >> 10) & 31, py = (cell >> 5) & 31, pz = cell & 31;
    int ex0 = px + ox - 1, ey0 = py + oy - 1, ez0 = pz + oz - 1;

    int pb[8];   // child-row base per corner: rank*8 or zero-block M_PTS
#pragma unroll
    for (int j = 0; j < 8; j++){
        int cx = ex0 + ((j >> 2) & 1), cy = ey0 + ((j >> 1) & 1), cz = ez0 + (j & 1);
        int base_ = M_PTS;
        if ((unsigned)cx < 32u && (unsigned)cy < 32u && (unsigned)cz < 32u){
            int pi = pg[cx * 1024 + cy * 32 + cz];
            if (pi >= 0) base_ = pi * 8;     // rank*8
        }
        pb[j] = base_;
    }

    float4v acc[16];
#pragma unroll
    for (int c = 0; c < 16; c++) acc[c] = 0.f;

#pragma unroll
    for (int t = 0; t < 27; t++){
        const int dx = t / 9 - 1, dy = (t / 3) % 3 - 1, dz = t % 3 - 1;
        int sx = ox + dx, sy = oy + dy, sz = oz + dz;
        int jx = (sx >> 1) - ox + 1, jy = (sy >> 1) - oy + 1, jz = (sz >> 1) - oz + 1;
        int opi = (sx & 1) * 4 + (sy & 1) * 2 + (sz & 1);
        int m00 = jz ? pb[1] : pb[0];
        int m01 = jz ? pb[3] : pb[2];
        int m10 = jz ? pb[5] : pb[4];
        int m11 = jz ? pb[7] : pb[6];
        int n0 = jy ? m01 : m00;
        int n1 = jy ? m11 : m10;
        int row = (jx ? n1 : n0) + opi;
        int fr0 = __shfl(row,      r16, 64);
        int fr1 = __shfl(row, 16 + r16, 64);
        int fr2 = __shfl(row, 32 + r16, 64);
        int fr3 = __shfl(row, 48 + r16, 64);
        const ushort* a0 = feat + (size_t)fr0 * C_OUT + qd * 8;
        const ushort* a1 = feat + (size_t)fr1 * C_OUT + qd * 8;
        const ushort* a2 = feat + (size_t)fr2 * C_OUT + qd * 8;
        const ushort* a3 = feat + (size_t)fr3 * C_OUT + qd * 8;
        const ushort* wt = Wt + (size_t)t * 4096 + l * 8;
#pragma unroll
        for (int kb = 0; kb < 2; kb++){
            short8 b0 = *(const short8*)(wt + (kb*4+0)*512);
            short8 b1 = *(const short8*)(wt + (kb*4+1)*512);
            short8 b2 = *(const short8*)(wt + (kb*4+2)*512);
            short8 b3 = *(const short8*)(wt + (kb*4+3)*512);
            short8 av0 = *(const short8*)(a0 + kb*32);
            short8 av1 = *(const short8*)(a1 + kb*32);
            short8 av2 = *(const short8*)(a2 + kb*32);
            short8 av3 = *(const short8*)(a3 + kb*32);
            acc[0]  = __builtin_amdgcn_mfma_f32_16x16x32_bf16(av0, b0, acc[0],  0, 0, 0);
            acc[1]  = __builtin_amdgcn_mfma_f32_16x16x32_bf16(av0, b1, acc[1],  0, 0, 0);
            acc[2]  = __builtin_amdgcn_mfma_f32_16x16x32_bf16(av0, b2, acc[2],  0, 0, 0);
            acc[3]  = __builtin_amdgcn_mfma_f32_16x16x32_bf16(av0, b3, acc[3],  0, 0, 0);
            acc[4]  = __builtin_amdgcn_mfma_f32_16x16x32_bf16(av1, b0, acc[4],  0, 0, 0);
            acc[5]  = __builtin_amdgcn_mfma_f32_16x16x32_bf16(av1, b1, acc[5],  0, 0, 0);
            acc[6]  = __builtin_amdgcn_mfma_f32_16x16x32_bf16(av1, b2, acc[6],  0, 0, 0);
            acc[7]  = __builtin_amdgcn_mfma_f32_16x16x32_bf16(av1, b3, acc[7],  0, 0, 0);
            acc[8]  = __builtin_amdgcn_mfma_f32_16x16x32_bf16(av2, b0, acc[8],  0, 0, 0);
            acc[9]  = __builtin_amdgcn_mfma_f32_16x16x32_bf16(av2, b1, acc[9],  0, 0, 0);
            acc[10] = __builtin_amdgcn_mfma_f32_16x16x32_bf16(av2, b2, acc[10], 0, 0, 0);
            acc[11] = __builtin_amdgcn_mfma_f32_16x16x32_bf16(av2, b3, acc[11], 0, 0, 0);
            acc[12] = __builtin_amdgcn_mfma_f32_16x16x32_bf16(av3, b0, acc[12], 0, 0, 0);
            acc[13] = __builtin_amdgcn_mfma_f32_16x16x32_bf16(av3, b1, acc[13], 0, 0, 0);
            acc[14] = __builtin_amdgcn_mfma_f32_16x16x32_bf16(av3, b2, acc[14], 0, 0, 0);
            acc[15] = __builtin_amdgcn_mfma_f32_16x16x32_bf16(av3, b3, acc[15], 0, 0, 0);
        }
    }

    float bsv[4] = { bias[r16], bias[16 + r16], bias[32 + r16], bias[48 + r16] };
#pragma unroll
    for (int rb = 0; rb < 4; rb++)
#pragma unroll
        for (int rg = 0; rg < 4; rg++){
            int sl = rb * 16 + qd * 4 + rg;
            int slt = mb + sl;
            if (slt < N_PTS){
                int spr = __shfl(sp, sl, 64);
                const float* sk = skip + (size_t)slt * 64;   // rank-ordered skip
#pragma unroll
                for (int nb = 0; nb < 4; nb++){
                    int co = nb * 16 + r16;
                    out[(size_t)(spr * 8 + o) * 64 + co] = acc[rb * 4 + nb][rg] + bsv[nb] + sk[co];
                }
            }
        }
}

// ================= K4: h2 = silu(gn2(hf1_bf16)) -> bf16 (slot order, linear) =================
__global__ void __launch_bounds__(256) h2_kernel(
    const ushort* __restrict__ hf1, const float* __restrict__ stats,
    const float* __restrict__ gg, const float* __restrict__ gb, ushort* __restrict__ h2)
{
    int i = (blockIdx.x * 256 + threadIdx.x) * 4;
    if (i >= M_PTS * C_OUT) return;
    int c0 = i & (C_OUT - 1);                    // multiple of 4
    const float inv = 1.0f / (M_PTS * 2.0f);
    float muA = (stats[64 + c0] + stats[64 + c0 + 1]) * inv;
    float vA  = (stats[128 + c0] + stats[128 + c0 + 1]) * inv - muA * muA;
    float rsA = rsqrtf(vA + EPS);
    float muB = (stats[64 + c0 + 2] + stats[64 + c0 + 3]) * inv;
    float vB  = (stats[128 + c0 + 2] + stats[128 + c0 + 3]) * inv - muB * muB;
    float rsB = rsqrtf(vB + EPS);
    ushort4 u = *(const ushort4*)(hf1 + i);
    ushort4 o;
    o.x = f2bf(silu((bf2f(u.x) - muA) * rsA * gg[c0+0] + gb[c0+0]));
    o.y = f2bf(silu((bf2f(u.y) - muA) * rsA * gg[c0+1] + gb[c0+1]));
    o.z = f2bf(silu((bf2f(u.z) - muB) * rsB * gg[c0+2] + gb[c0+2]));
    o.w = f2bf(silu((bf2f(u.w) - muB) * rsB * gg[c0+3] + gb[c0+3]));
    *(ushort4*)(h2 + i) = o;
}

extern "C" void kernel_launch(void* const* d_in, const int* in_sizes, int n_in,
                              void* d_out, int out_size, void* d_ws, size_t ws_size,
                              hipStream_t stream){
    const float* x   = (const float*)d_in[0];
    const int*   cds = (const int*)  d_in[1];
    const float* g1  = (const float*)d_in[2];
    const float* b1  = (const float*)d_in[3];
    const float* W1  = (const float*)d_in[4];
    const float* bb1 = (const float*)d_in[5];
    const float* g2  = (const float*)d_in[6];
    const float* b2  = (const float*)d_in[7];
    const float* W2  = (const float*)d_in[8];
    const float* bb2 = (const float*)d_in[9];
    const float* Wsk = (const float*)d_in[10];
    const float* bsk = (const float*)d_in[11];
    float* out = (float*)d_out;
    char* ws = (char*)d_ws;

    // workspace layout (16B-aligned); high-water 32,211,328 B
    float*  stats = (float*) (ws);                 // 192 f32 (zeroed via memsetAsync)
    int*    pg    = (int*)   (ws + 1024);          // 131072 B -> 132096
    ushort* h     = (ushort*)(ws + 132096);        // (N+1)*128 bf16 = 5,120,256 -> 5,252,352
    ushort* h2    = (ushort*)(ws + 5252352);       // (M+8)*64 bf16 = 20,481,024 -> 25,733,376
    float*  s     = (float*) (ws + 25733376);      // N*64 f32 = 5,120,000 -> 30,853,376
    ushort* Wt1   = (ushort*)(ws + 30853376);      // W1eff 1,048,576 -> 31,901,952
    ushort* Wt2   = (ushort*)(ws + 31901952);      // 221,184 -> 32,123,136
    unsigned int* ordp = (unsigned int*)(ws + 32123136); // 80,000 -> 32,203,136
    int*    cnt   = (int*)   (ws + 32203136);      // 4096 -> 32,207,232
    int*    base  = (int*)   (ws + 32207232);      // 4096 -> 32,211,328
    // hf1 (bf16, M*64, slot order) lives in d_out between conv1 and h2_kernel.

    hipMemsetAsync(stats, 0, 192 * sizeof(float), stream);
    prep_kernel<<<3120, 256, 0, stream>>>(W1, W2, Wt1, Wt2, pg, h, h2, x, stats);
    scatter_kernel<<<79, 256, 0, stream>>>(cds, pg);
    sortA_kernel<<<16, 64, 0, stream>>>(pg, cnt);
    sortB_kernel<<<1, 1024, 0, stream>>>(cnt, base);
    sortC_kernel<<<16, 64, 0, stream>>>(pg, ordp, base);
    mid_kernel<<<7500, 256, 0, stream>>>(cds, pg, x, stats, g1, b1, h, Wsk, bsk, s);
    conv1_halo<<<512, 512, 0, stream>>>(h, pg, ordp, base, Wt1, bb1,
                                        (ushort*)d_out, stats);
    h2_kernel<<<12500, 256, 0, stream>>>((const ushort*)d_out, stats, g2, b2, h2);
    conv2_corner<<<626, 256, 0, stream>>>(h2, pg, ordp, Wt2, bb2, s, out);
}

// Round 13
// 353.100 us; speedup vs baseline: 1.1310x; 1.1310x over previous
//
#include <hip/hip_runtime.h>
#include <hip/hip_bf16.h>
#include <math.h>

#define N_PTS 20000
#define C_IN 128
#define C_OUT 64
#define M_PTS (N_PTS*8)
#define EPS 1e-5f

typedef __attribute__((ext_vector_type(8))) short short8;
typedef __attribute__((ext_vector_type(4))) float float4v;

__device__ __forceinline__ ushort f2bf(float f){
    unsigned int i = __float_as_uint(f);
    unsigned int r = i + 0x7fffu + ((i >> 16) & 1u);
    return (ushort)(r >> 16);
}
__device__ __forceinline__ float bf2f(ushort u){ return __uint_as_float(((unsigned int)u) << 16); }
__device__ __forceinline__ float silu(float z){ return z / (1.f + expf(-z)); }

// stats layout (fp32, ws): [0..31] gn1 group sum, [32..63] gn1 group sumsq,
//                          [64..127] gn2 ch sum, [128..191] gn2 ch sumsq

// ================= K1: W1eff + wprep2 + pg_init(+zero rows) + gn1_partial =================
// blocks: [0,2048) W1eff, [2048,2480) Wt2, [2480,2608) pg_init, [2608,3120) gn1
// W1eff[o][j] = sum over taps d with per-axis (o_x+d_x)>>1 == o_x+j_x-1 of W1[d].
// Thread->element mapping puts co's low 4 bits in the lane's low bits so the
// W1/W2 reads are 64B-coalesced per 16 lanes (was 4B reads at 256B stride).
__global__ void __launch_bounds__(256) prep_kernel(
    const float* __restrict__ W1, const float* __restrict__ W2,
    ushort* __restrict__ Wt1, ushort* __restrict__ Wt2,
    int* __restrict__ pg, ushort* __restrict__ h, ushort* __restrict__ h2,
    const float* __restrict__ x, float* __restrict__ stats)
{
    const int b = blockIdx.x, tid = threadIdx.x;
    if (b < 2048){
        // Wt1eff fragment order: idx = (((t*4+kb)*4+nb)*64+l)*8+j, t = o*8+jj in [0,64)
        // coalesced decomposition: cl (co low) fastest
        int e = b * 256 + tid;
        int cl = e & 15, j = (e >> 4) & 7, lh = (e >> 7) & 3, nb = (e >> 9) & 3, kb = (e >> 11) & 3, t = e >> 13;
        int l = lh * 16 + cl;
        int ci = kb * 32 + lh * 8 + j, co = nb * 16 + cl;
        int o = t >> 3, jj = t & 7;
        int ox = (o >> 2) & 1, oy = (o >> 1) & 1, oz = o & 1;
        int jx = (jj >> 2) & 1, jy = (jj >> 1) & 1, jz = jj & 1;
        float s = 0.f;
#pragma unroll
        for (int dx = -1; dx <= 1; dx++){
            if (((ox + dx) >> 1) != ox + jx - 1) continue;
#pragma unroll
            for (int dy = -1; dy <= 1; dy++){
                if (((oy + dy) >> 1) != oy + jy - 1) continue;
#pragma unroll
                for (int dz = -1; dz <= 1; dz++){
                    if (((oz + dz) >> 1) != oz + jz - 1) continue;
                    s += W1[((dx+1)*9 + (dy+1)*3 + (dz+1)) * (C_IN*64) + ci * 64 + co];
                }
            }
        }
        Wt1[(((t*4+kb)*4+nb)*64+l)*8+j] = f2bf(s);
    } else if (b < 2480){
        // Wt2 fragment order: idx = (((t*2+kb)*4+nb)*64+l)*8+j, KB=2, t in [0,27)
        int e = (b - 2048) * 256 + tid;
        int cl = e & 15, j = (e >> 4) & 7, lh = (e >> 7) & 3, nb = (e >> 9) & 3, kb = (e >> 11) & 1, t = e >> 12;
        int l = lh * 16 + cl;
        int ci = kb * 32 + lh * 8 + j, co = nb * 16 + cl;
        Wt2[(((t*2+kb)*4+nb)*64+l)*8+j] = f2bf(W2[(t * C_OUT + ci) * 64 + co]);
    } else if (b < 2608){
        int i = (b - 2480) * 256 + tid;
        pg[i] = -1;
        if (b == 2480){
            if (tid < C_IN) h[(size_t)N_PTS * C_IN + tid] = 0;    // zero parent row (conv1)
            if (tid < 256){                                        // 8 zero child rows (conv2)
                h2[(size_t)M_PTS * C_OUT + tid] = 0;
                h2[(size_t)M_PTS * C_OUT + 256 + tid] = 0;
            }
        }
    } else {
        // gn1 partial: 512 blocks, grid-stride rows, LDS + global atomics
        __shared__ float ls[64];
        if (tid < 64) ls[tid] = 0.f;
        __syncthreads();
        const int g = tid & 31;
        const int r0 = (b - 2608) * 8 + (tid >> 5);
        float sum = 0.f, sq = 0.f;
        for (int r = r0; r < N_PTS; r += 4096){
            float4 v = *(const float4*)(x + (size_t)r * C_IN + g * 4);
            sum += v.x + v.y + v.z + v.w;
            sq  += v.x*v.x + v.y*v.y + v.z*v.z + v.w*v.w;
        }
        atomicAdd(&ls[g], sum);
        atomicAdd(&ls[32 + g], sq);
        __syncthreads();
        if (tid < 64) atomicAdd(&stats[tid], ls[tid]);
    }
}

// ================= K2: pg_scatter + h_compute + skip =================
// blocks: [0,79) scatter, [79,2579) h (vec4), [2579,7579) skip
__global__ void __launch_bounds__(256) mid_kernel(
    const int* __restrict__ cds, int* __restrict__ pg,
    const float* __restrict__ x, const float* __restrict__ stats,
    const float* __restrict__ g1, const float* __restrict__ b1, ushort* __restrict__ h,
    const float* __restrict__ Wsk, const float* __restrict__ bsk, float* __restrict__ s)
{
    __shared__ float w[C_IN * C_OUT];
    const int b = blockIdx.x, tid = threadIdx.x;
    if (b < 79){
        int i = b * 256 + tid;
        if (i < N_PTS){
            const int* cd = cds + i * 4;
            pg[(cd[1] * 32 + cd[2]) * 32 + cd[3]] = i;
        }
    } else if (b < 2579){
        int i = ((b - 79) * 256 + tid) * 4;
        int c0 = i & (C_IN - 1);                  // multiple of 4 -> one group
        int g = c0 >> 2;
        float mu = stats[g] * (1.0f / (N_PTS * 4.0f));
        float var = stats[32 + g] * (1.0f / (N_PTS * 4.0f)) - mu * mu;
        float rs = rsqrtf(var + EPS);
        float4 v = *(const float4*)(x + i);
        ushort4 o;
        o.x = f2bf(silu((v.x - mu) * rs * g1[c0+0] + b1[c0+0]));
        o.y = f2bf(silu((v.y - mu) * rs * g1[c0+1] + b1[c0+1]));
        o.z = f2bf(silu((v.z - mu) * rs * g1[c0+2] + b1[c0+2]));
        o.w = f2bf(silu((v.w - mu) * rs * g1[c0+3] + b1[c0+3]));
        *(ushort4*)(h + i) = o;
    } else {
        for (int j = tid; j < C_IN * C_OUT; j += 256) w[j] = Wsk[j];
        __syncthreads();
        int co = tid & 63, pr = tid >> 6;
        int p = (b - 2579) * 4 + pr;
        const float* xr = x + (size_t)p * C_IN;
        float a = bsk[co];
        for (int cb = 0; cb < C_IN; cb += 4){
            float4 v = *(const float4*)(xr + cb);
            a += v.x * w[(cb+0)*64+co] + v.y * w[(cb+1)*64+co]
               + v.z * w[(cb+2)*64+co] + v.w * w[(cb+3)*64+co];
        }
        s[(size_t)p * C_OUT + co] = a;
    }
}

// ================= conv1: corner-collapsed implicit GEMM =================
// grid (313, 8): blockIdx.x = 64-parent tile, blockIdx.y = octant o.
// M-tile = 64 parents (children (p,o)), N = 64, 8 corner taps of K=128 with W1eff.
// A rows = parent feature rows (h). 8 pg lookups per lane, hoisted; shfl exchange.
// Fused: bias, hf1 bf16 write, GN2 partial sums (padding rows excluded).
__global__ void __launch_bounds__(64, 3) conv1_corner(
    const ushort* __restrict__ feat, const int* __restrict__ pg,
    const int* __restrict__ coords, const ushort* __restrict__ Wt,
    const float* __restrict__ bias, ushort* __restrict__ hf1_bf,
    float* __restrict__ statsAcc)
{
    const int l = threadIdx.x;
    const int r16 = l & 15, qd = l >> 4;
    const int bx = blockIdx.x, o = blockIdx.y;

    int p = bx * 64 + l;
    int pc = p < N_PTS ? p : N_PTS - 1;
    int px = coords[pc*4+1], py = coords[pc*4+2], pz = coords[pc*4+3];
    // corner base: e = o_bit - 1 + j_bit per axis
    int ex0 = px + ((o >> 2) & 1) - 1;
    int ey0 = py + ((o >> 1) & 1) - 1;
    int ez0 = pz + (o & 1) - 1;

    int rows8[8];
#pragma unroll
    for (int j = 0; j < 8; j++){
        int cx = ex0 + ((j >> 2) & 1), cy = ey0 + ((j >> 1) & 1), cz = ez0 + (j & 1);
        int row = N_PTS;
        if ((unsigned)cx < 32u && (unsigned)cy < 32u && (unsigned)cz < 32u){
            int pi = pg[cx * 1024 + cy * 32 + cz];
            if (pi >= 0) row = pi;
        }
        rows8[j] = row;
    }

    float4v acc[16];
#pragma unroll
    for (int c = 0; c < 16; c++) acc[c] = 0.f;

#pragma unroll
    for (int j = 0; j < 8; j++){
        int fr0 = __shfl(rows8[j],      r16, 64);
        int fr1 = __shfl(rows8[j], 16 + r16, 64);
        int fr2 = __shfl(rows8[j], 32 + r16, 64);
        int fr3 = __shfl(rows8[j], 48 + r16, 64);
        const ushort* a0 = feat + (size_t)fr0 * C_IN + qd * 8;
        const ushort* a1 = feat + (size_t)fr1 * C_IN + qd * 8;
        const ushort* a2 = feat + (size_t)fr2 * C_IN + qd * 8;
        const ushort* a3 = feat + (size_t)fr3 * C_IN + qd * 8;
        const ushort* wt = Wt + (size_t)(o * 8 + j) * 8192 + l * 8;
#pragma unroll
        for (int kb = 0; kb < 4; kb++){
            short8 b0 = *(const short8*)(wt + (kb*4+0)*512);
            short8 b1 = *(const short8*)(wt + (kb*4+1)*512);
            short8 b2 = *(const short8*)(wt + (kb*4+2)*512);
            short8 b3 = *(const short8*)(wt + (kb*4+3)*512);
            short8 av0 = *(const short8*)(a0 + kb*32);
            short8 av1 = *(const short8*)(a1 + kb*32);
            short8 av2 = *(const short8*)(a2 + kb*32);
            short8 av3 = *(const short8*)(a3 + kb*32);
            acc[0]  = __builtin_amdgcn_mfma_f32_16x16x32_bf16(av0, b0, acc[0],  0, 0, 0);
            acc[1]  = __builtin_amdgcn_mfma_f32_16x16x32_bf16(av0, b1, acc[1],  0, 0, 0);
            acc[2]  = __builtin_amdgcn_mfma_f32_16x16x32_bf16(av0, b2, acc[2],  0, 0, 0);
            acc[3]  = __builtin_amdgcn_mfma_f32_16x16x32_bf16(av0, b3, acc[3],  0, 0, 0);
            acc[4]  = __builtin_amdgcn_mfma_f32_16x16x32_bf16(av1, b0, acc[4],  0, 0, 0);
            acc[5]  = __builtin_amdgcn_mfma_f32_16x16x32_bf16(av1, b1, acc[5],  0, 0, 0);
            acc[6]  = __builtin_amdgcn_mfma_f32_16x16x32_bf16(av1, b2, acc[6],  0, 0, 0);
            acc[7]  = __builtin_amdgcn_mfma_f32_16x16x32_bf16(av1, b3, acc[7],  0, 0, 0);
            acc[8]  = __builtin_amdgcn_mfma_f32_16x16x32_bf16(av2, b0, acc[8],  0, 0, 0);
            acc[9]  = __builtin_amdgcn_mfma_f32_16x16x32_bf16(av2, b1, acc[9],  0, 0, 0);
            acc[10] = __builtin_amdgcn_mfma_f32_16x16x32_bf16(av2, b2, acc[10], 0, 0, 0);
            acc[11] = __builtin_amdgcn_mfma_f32_16x16x32_bf16(av2, b3, acc[11], 0, 0, 0);
            acc[12] = __builtin_amdgcn_mfma_f32_16x16x32_bf16(av3, b0, acc[12], 0, 0, 0);
            acc[13] = __builtin_amdgcn_mfma_f32_16x16x32_bf16(av3, b1, acc[13], 0, 0, 0);
            acc[14] = __builtin_amdgcn_mfma_f32_16x16x32_bf16(av3, b2, acc[14], 0, 0, 0);
            acc[15] = __builtin_amdgcn_mfma_f32_16x16x32_bf16(av3, b3, acc[15], 0, 0, 0);
        }
    }

    // epilogue: C/D layout col = lane&15, row = (lane>>4)*4 + reg; row-in-tile = parent
    float bsv[4] = { bias[r16], bias[16 + r16], bias[32 + r16], bias[48 + r16] };
    float ps[4] = {0,0,0,0}, pq[4] = {0,0,0,0};
#pragma unroll
    for (int rb = 0; rb < 4; rb++)
#pragma unroll
        for (int nb = 0; nb < 4; nb++)
#pragma unroll
            for (int rg = 0; rg < 4; rg++){
                int pr = bx * 64 + rb * 16 + qd * 4 + rg;
                float v = acc[rb * 4 + nb][rg] + bsv[nb];
                if (pr < N_PTS){
                    hf1_bf[(size_t)(pr * 8 + o) * 64 + nb * 16 + r16] = f2bf(v);
                    ps[nb] += v; pq[nb] += v * v;
                }
            }
#pragma unroll
    for (int nb = 0; nb < 4; nb++){
        float s1 = ps[nb], s2 = pq[nb];
        s1 += __shfl_xor(s1, 16, 64); s2 += __shfl_xor(s2, 16, 64);
        s1 += __shfl_xor(s1, 32, 64); s2 += __shfl_xor(s2, 32, 64);
        if (qd == 0){
            atomicAdd(&statsAcc[64 + nb * 16 + r16], s1);
            atomicAdd(&statsAcc[128 + nb * 16 + r16], s2);
        }
    }
}

// ================= conv2: corner-based implicit GEMM =================
// grid (313, 8). M-tile = 64 children (64 parents, fixed octant o), N=64, 27 taps K=64.
// Only 8 pg lookups; tap t's A row = pidx8[j(o,t)]*8 + o'(o,t) via constant-index
// select tree (j bits are block-uniform). Adds skip, writes fp32 out.
__global__ void __launch_bounds__(64, 3) conv2_corner(
    const ushort* __restrict__ feat, const int* __restrict__ pg,
    const int* __restrict__ coords, const ushort* __restrict__ Wt,
    const float* __restrict__ bias, const float* __restrict__ skip,
    float* __restrict__ out)
{
    const int l = threadIdx.x;
    const int r16 = l & 15, qd = l >> 4;
    const int bx = blockIdx.x, o = blockIdx.y;
    const int ox = (o >> 2) & 1, oy = (o >> 1) & 1, oz = o & 1;

    int p = bx * 64 + l;
    int pc = p < N_PTS ? p : N_PTS - 1;
    int px = coords[pc*4+1], py = coords[pc*4+2], pz = coords[pc*4+3];
    int ex0 = px + ox - 1, ey0 = py + oy - 1, ez0 = pz + oz - 1;

    int pb[8];   // child-row base per corner: pidx*8 or zero-block M_PTS
#pragma unroll
    for (int j = 0; j < 8; j++){
        int cx = ex0 + ((j >> 2) & 1), cy = ey0 + ((j >> 1) & 1), cz = ez0 + (j & 1);
        int base = M_PTS;
        if ((unsigned)cx < 32u && (unsigned)cy < 32u && (unsigned)cz < 32u){
            int pi = pg[cx * 1024 + cy * 32 + cz];
            if (pi >= 0) base = pi * 8;
        }
        pb[j] = base;
    }

    float4v acc[16];
#pragma unroll
    for (int c = 0; c < 16; c++) acc[c] = 0.f;

#pragma unroll
    for (int t = 0; t < 27; t++){
        const int dx = t / 9 - 1, dy = (t / 3) % 3 - 1, dz = t % 3 - 1;
        int sx = ox + dx, sy = oy + dy, sz = oz + dz;
        int jx = (sx >> 1) - ox + 1, jy = (sy >> 1) - oy + 1, jz = (sz >> 1) - oz + 1;
        int opi = (sx & 1) * 4 + (sy & 1) * 2 + (sz & 1);
        // constant-index select tree (jx/jy/jz block-uniform 0/1)
        int m00 = jz ? pb[1] : pb[0];
        int m01 = jz ? pb[3] : pb[2];
        int m10 = jz ? pb[5] : pb[4];
        int m11 = jz ? pb[7] : pb[6];
        int n0 = jy ? m01 : m00;
        int n1 = jy ? m11 : m10;
        int row = (jx ? n1 : n0) + opi;
        int fr0 = __shfl(row,      r16, 64);
        int fr1 = __shfl(row, 16 + r16, 64);
        int fr2 = __shfl(row, 32 + r16, 64);
        int fr3 = __shfl(row, 48 + r16, 64);
        const ushort* a0 = feat + (size_t)fr0 * C_OUT + qd * 8;
        const ushort* a1 = feat + (size_t)fr1 * C_OUT + qd * 8;
        const ushort* a2 = feat + (size_t)fr2 * C_OUT + qd * 8;
        const ushort* a3 = feat + (size_t)fr3 * C_OUT + qd * 8;
        const ushort* wt = Wt + (size_t)t * 4096 + l * 8;
#pragma unroll
        for (int kb = 0; kb < 2; kb++){
            short8 b0 = *(const short8*)(wt + (kb*4+0)*512);
            short8 b1 = *(const short8*)(wt + (kb*4+1)*512);
            short8 b2 = *(const short8*)(wt + (kb*4+2)*512);
            short8 b3 = *(const short8*)(wt + (kb*4+3)*512);
            short8 av0 = *(const short8*)(a0 + kb*32);
            short8 av1 = *(const short8*)(a1 + kb*32);
            short8 av2 = *(const short8*)(a2 + kb*32);
            short8 av3 = *(const short8*)(a3 + kb*32);
            acc[0]  = __builtin_amdgcn_mfma_f32_16x16x32_bf16(av0, b0, acc[0],  0, 0, 0);
            acc[1]  = __builtin_amdgcn_mfma_f32_16x16x32_bf16(av0, b1, acc[1],  0, 0, 0);
            acc[2]  = __builtin_amdgcn_mfma_f32_16x16x32_bf16(av0, b2, acc[2],  0, 0, 0);
            acc[3]  = __builtin_amdgcn_mfma_f32_16x16x32_bf16(av0, b3, acc[3],  0, 0, 0);
            acc[4]  = __builtin_amdgcn_mfma_f32_16x16x32_bf16(av1, b0, acc[4],  0, 0, 0);
            acc[5]  = __builtin_amdgcn_mfma_f32_16x16x32_bf16(av1, b1, acc[5],  0, 0, 0);
            acc[6]  = __builtin_amdgcn_mfma_f32_16x16x32_bf16(av1, b2, acc[6],  0, 0, 0);
            acc[7]  = __builtin_amdgcn_mfma_f32_16x16x32_bf16(av1, b3, acc[7],  0, 0, 0);
            acc[8]  = __builtin_amdgcn_mfma_f32_16x16x32_bf16(av2, b0, acc[8],  0, 0, 0);
            acc[9]  = __builtin_amdgcn_mfma_f32_16x16x32_bf16(av2, b1, acc[9],  0, 0, 0);
            acc[10] = __builtin_amdgcn_mfma_f32_16x16x32_bf16(av2, b2, acc[10], 0, 0, 0);
            acc[11] = __builtin_amdgcn_mfma_f32_16x16x32_bf16(av2, b3, acc[11], 0, 0, 0);
            acc[12] = __builtin_amdgcn_mfma_f32_16x16x32_bf16(av3, b0, acc[12], 0, 0, 0);
            acc[13] = __builtin_amdgcn_mfma_f32_16x16x32_bf16(av3, b1, acc[13], 0, 0, 0);
            acc[14] = __builtin_amdgcn_mfma_f32_16x16x32_bf16(av3, b2, acc[14], 0, 0, 0);
            acc[15] = __builtin_amdgcn_mfma_f32_16x16x32_bf16(av3, b3, acc[15], 0, 0, 0);
        }
    }

    float bsv[4] = { bias[r16], bias[16 + r16], bias[32 + r16], bias[48 + r16] };
#pragma unroll
    for (int rb = 0; rb < 4; rb++)
#pragma unroll
        for (int rg = 0; rg < 4; rg++){
            int pr = bx * 64 + rb * 16 + qd * 4 + rg;
            if (pr < N_PTS){
                const float* sk = skip + (size_t)pr * 64;
#pragma unroll
                for (int nb = 0; nb < 4; nb++){
                    int co = nb * 16 + r16;
                    out[(size_t)(pr * 8 + o) * 64 + co] = acc[rb * 4 + nb][rg] + bsv[nb] + sk[co];
                }
            }
        }
}

// ================= K4: h2 = silu(gn2(hf1_bf16)) -> bf16 =================
__global__ void __launch_bounds__(256) h2_kernel(
    const ushort* __restrict__ hf1, const float* __restrict__ stats,
    const float* __restrict__ gg, const float* __restrict__ gb, ushort* __restrict__ h2)
{
    int i = (blockIdx.x * 256 + threadIdx.x) * 4;
    if (i >= M_PTS * C_OUT) return;
    int c0 = i & (C_OUT - 1);                    // multiple of 4
    const float inv = 1.0f / (M_PTS * 2.0f);
    float muA = (stats[64 + c0] + stats[64 + c0 + 1]) * inv;
    float vA  = (stats[128 + c0] + stats[128 + c0 + 1]) * inv - muA * muA;
    float rsA = rsqrtf(vA + EPS);
    float muB = (stats[64 + c0 + 2] + stats[64 + c0 + 3]) * inv;
    float vB  = (stats[128 + c0 + 2] + stats[128 + c0 + 3]) * inv - muB * muB;
    float rsB = rsqrtf(vB + EPS);
    ushort4 u = *(const ushort4*)(hf1 + i);
    ushort4 o;
    o.x = f2bf(silu((bf2f(u.x) - muA) * rsA * gg[c0+0] + gb[c0+0]));
    o.y = f2bf(silu((bf2f(u.y) - muA) * rsA * gg[c0+1] + gb[c0+1]));
    o.z = f2bf(silu((bf2f(u.z) - muB) * rsB * gg[c0+2] + gb[c0+2]));
    o.w = f2bf(silu((bf2f(u.w) - muB) * rsB * gg[c0+3] + gb[c0+3]));
    *(ushort4*)(h2 + i) = o;
}

extern "C" void kernel_launch(void* const* d_in, const int* in_sizes, int n_in,
                              void* d_out, int out_size, void* d_ws, size_t ws_size,
                              hipStream_t stream){
    const float* x   = (const float*)d_in[0];
    const int*   cds = (const int*)  d_in[1];
    const float* g1  = (const float*)d_in[2];
    const float* b1  = (const float*)d_in[3];
    const float* W1  = (const float*)d_in[4];
    const float* bb1 = (const float*)d_in[5];
    const float* g2  = (const float*)d_in[6];
    const float* b2  = (const float*)d_in[7];
    const float* W2  = (const float*)d_in[8];
    const float* bb2 = (const float*)d_in[9];
    const float* Wsk = (const float*)d_in[10];
    const float* bsk = (const float*)d_in[11];
    float* out = (float*)d_out;
    char* ws = (char*)d_ws;

    // workspace layout (16B-aligned); high-water 32,123,136 B (round-5-proven)
    float*  stats = (float*) (ws);                 // 192 f32 (zeroed via memsetAsync)
    int*    pg    = (int*)   (ws + 1024);          // 131072 B -> 132096
    ushort* h     = (ushort*)(ws + 132096);        // (N+1)*128 bf16 = 5,120,256 -> 5,252,352
    ushort* h2    = (ushort*)(ws + 5252352);       // (M+8)*64 bf16 = 20,481,024 -> 25,733,376
    float*  s     = (float*) (ws + 25733376);      // N*64 f32 = 5,120,000 -> 30,853,376
    ushort* Wt1   = (ushort*)(ws + 30853376);      // W1eff 64*8192*2 = 1,048,576 -> 31,901,952
    ushort* Wt2   = (ushort*)(ws + 31901952);      // 221,184 -> 32,123,136
    // hf1 (bf16, M*64) lives in d_out between conv1 and h2_kernel; conv2 overwrites d_out as f32.

    hipMemsetAsync(stats, 0, 192 * sizeof(float), stream);
    prep_kernel<<<3120, 256, 0, stream>>>(W1, W2, Wt1, Wt2, pg, h, h2, x, stats);
    mid_kernel<<<7579, 256, 0, stream>>>(cds, pg, x, stats, g1, b1, h, Wsk, bsk, s);
    conv1_corner<<<dim3(313, 8), 64, 0, stream>>>(h, pg, cds, Wt1, bb1,
                                                  (ushort*)d_out, stats);
    h2_kernel<<<12500, 256, 0, stream>>>((const ushort*)d_out, stats, g2, b2, h2);
    conv2_corner<<<dim3(313, 8), 64, 0, stream>>>(h2, pg, cds, Wt2, bb2, s, out);
}

// Round 14
// 343.139 us; speedup vs baseline: 1.1638x; 1.0290x over previous
//
#include <hip/hip_runtime.h>
#include <hip/hip_bf16.h>
#include <math.h>

#define N_PTS 20000
#define C_IN 128
#define C_OUT 64
#define M_PTS (N_PTS*8)
#define EPS 1e-5f

typedef __attribute__((ext_vector_type(8))) short short8;
typedef __attribute__((ext_vector_type(4))) float float4v;

__device__ __forceinline__ ushort f2bf(float f){
    unsigned int i = __float_as_uint(f);
    unsigned int r = i + 0x7fffu + ((i >> 16) & 1u);
    return (ushort)(r >> 16);
}
__device__ __forceinline__ float bf2f(ushort u){ return __uint_as_float(((unsigned int)u) << 16); }
__device__ __forceinline__ float silu(float z){ return z / (1.f + expf(-z)); }

// stats layout (fp32, ws): [0..31] gn1 group sum, [32..63] gn1 group sumsq,
//                          [64..127] gn2 ch sum, [128..191] gn2 ch sumsq

// ================= K1: W1eff + wprep2 + pg_init(+zero rows) + gn1_partial =================
// blocks: [0,2048) W1eff, [2048,2480) Wt2, [2480,2608) pg_init, [2608,3120) gn1
// W1eff[o][j] = sum over taps d with per-axis (o_x+d_x)>>1 == o_x+j_x-1 of W1[d].
__global__ void __launch_bounds__(256) prep_kernel(
    const float* __restrict__ W1, const float* __restrict__ W2,
    ushort* __restrict__ Wt1, ushort* __restrict__ Wt2,
    int* __restrict__ pg, ushort* __restrict__ h, ushort* __restrict__ h2,
    const float* __restrict__ x, float* __restrict__ stats)
{
    const int b = blockIdx.x, tid = threadIdx.x;
    if (b < 2048){
        // Wt1eff fragment order: idx = (((t*4+kb)*4+nb)*64+l)*8+j, t = o*8+jj in [0,64)
        // coalesced decomposition: cl (co low) fastest
        int e = b * 256 + tid;
        int cl = e & 15, j = (e >> 4) & 7, lh = (e >> 7) & 3, nb = (e >> 9) & 3, kb = (e >> 11) & 3, t = e >> 13;
        int l = lh * 16 + cl;
        int ci = kb * 32 + lh * 8 + j, co = nb * 16 + cl;
        int o = t >> 3, jj = t & 7;
        int ox = (o >> 2) & 1, oy = (o >> 1) & 1, oz = o & 1;
        int jx = (jj >> 2) & 1, jy = (jj >> 1) & 1, jz = jj & 1;
        float s = 0.f;
#pragma unroll
        for (int dx = -1; dx <= 1; dx++){
            if (((ox + dx) >> 1) != ox + jx - 1) continue;
#pragma unroll
            for (int dy = -1; dy <= 1; dy++){
                if (((oy + dy) >> 1) != oy + jy - 1) continue;
#pragma unroll
                for (int dz = -1; dz <= 1; dz++){
                    if (((oz + dz) >> 1) != oz + jz - 1) continue;
                    s += W1[((dx+1)*9 + (dy+1)*3 + (dz+1)) * (C_IN*64) + ci * 64 + co];
                }
            }
        }
        Wt1[(((t*4+kb)*4+nb)*64+l)*8+j] = f2bf(s);
    } else if (b < 2480){
        // Wt2 fragment order: idx = (((t*2+kb)*4+nb)*64+l)*8+j, KB=2, t in [0,27)
        int e = (b - 2048) * 256 + tid;
        int cl = e & 15, j = (e >> 4) & 7, lh = (e >> 7) & 3, nb = (e >> 9) & 3, kb = (e >> 11) & 1, t = e >> 12;
        int l = lh * 16 + cl;
        int ci = kb * 32 + lh * 8 + j, co = nb * 16 + cl;
        Wt2[(((t*2+kb)*4+nb)*64+l)*8+j] = f2bf(W2[(t * C_OUT + ci) * 64 + co]);
    } else if (b < 2608){
        int i = (b - 2480) * 256 + tid;
        pg[i] = -1;
        if (b == 2480){
            if (tid < C_IN) h[(size_t)N_PTS * C_IN + tid] = 0;    // zero parent row (conv1)
            if (tid < 256){                                        // 8 zero rows (conv2, octant-major)
                h2[(size_t)M_PTS * C_OUT + tid] = 0;
                h2[(size_t)M_PTS * C_OUT + 256 + tid] = 0;
            }
        }
    } else {
        // gn1 partial: 512 blocks, grid-stride rows, LDS + global atomics
        __shared__ float ls[64];
        if (tid < 64) ls[tid] = 0.f;
        __syncthreads();
        const int g = tid & 31;
        const int r0 = (b - 2608) * 8 + (tid >> 5);
        float sum = 0.f, sq = 0.f;
        for (int r = r0; r < N_PTS; r += 4096){
            float4 v = *(const float4*)(x + (size_t)r * C_IN + g * 4);
            sum += v.x + v.y + v.z + v.w;
            sq  += v.x*v.x + v.y*v.y + v.z*v.z + v.w*v.w;
        }
        atomicAdd(&ls[g], sum);
        atomicAdd(&ls[32 + g], sq);
        __syncthreads();
        if (tid < 64) atomicAdd(&stats[tid], ls[tid]);
    }
}

// ================= K2: pg_scatter + h_compute + skip =================
// blocks: [0,79) scatter, [79,2579) h (vec4), [2579,7579) skip
__global__ void __launch_bounds__(256) mid_kernel(
    const int* __restrict__ cds, int* __restrict__ pg,
    const float* __restrict__ x, const float* __restrict__ stats,
    const float* __restrict__ g1, const float* __restrict__ b1, ushort* __restrict__ h,
    const float* __restrict__ Wsk, const float* __restrict__ bsk, float* __restrict__ s)
{
    __shared__ float w[C_IN * C_OUT];
    const int b = blockIdx.x, tid = threadIdx.x;
    if (b < 79){
        int i = b * 256 + tid;
        if (i < N_PTS){
            const int* cd = cds + i * 4;
            pg[(cd[1] * 32 + cd[2]) * 32 + cd[3]] = i;
        }
    } else if (b < 2579){
        int i = ((b - 79) * 256 + tid) * 4;
        int c0 = i & (C_IN - 1);                  // multiple of 4 -> one group
        int g = c0 >> 2;
        float mu = stats[g] * (1.0f / (N_PTS * 4.0f));
        float var = stats[32 + g] * (1.0f / (N_PTS * 4.0f)) - mu * mu;
        float rs = rsqrtf(var + EPS);
        float4 v = *(const float4*)(x + i);
        ushort4 o;
        o.x = f2bf(silu((v.x - mu) * rs * g1[c0+0] + b1[c0+0]));
        o.y = f2bf(silu((v.y - mu) * rs * g1[c0+1] + b1[c0+1]));
        o.z = f2bf(silu((v.z - mu) * rs * g1[c0+2] + b1[c0+2]));
        o.w = f2bf(silu((v.w - mu) * rs * g1[c0+3] + b1[c0+3]));
        *(ushort4*)(h + i) = o;
    } else {
        for (int j = tid; j < C_IN * C_OUT; j += 256) w[j] = Wsk[j];
        __syncthreads();
        int co = tid & 63, pr = tid >> 6;
        int p = (b - 2579) * 4 + pr;
        const float* xr = x + (size_t)p * C_IN;
        float a = bsk[co];
        for (int cb = 0; cb < C_IN; cb += 4){
            float4 v = *(const float4*)(xr + cb);
            a += v.x * w[(cb+0)*64+co] + v.y * w[(cb+1)*64+co]
               + v.z * w[(cb+2)*64+co] + v.w * w[(cb+3)*64+co];
        }
        s[(size_t)p * C_OUT + co] = a;
    }
}

// ================= conv1: corner-collapsed implicit GEMM, octant-major hf1 =================
// grid (313, 8): blockIdx.x = 64-parent tile, blockIdx.y = octant o.
// M-tile = 64 parents (children (p,o)), N = 64, 8 corner taps of K=128 with W1eff.
// hf1 is written OCTANT-MAJOR [o][p][64]: block (bx,o) writes rows o*N+p for
// consecutive p -> 16KB contiguous, full cache lines, no write-RMW.
// Fused: bias, hf1 bf16 write, GN2 partial sums (padding rows excluded).
__global__ void __launch_bounds__(64, 3) conv1_corner(
    const ushort* __restrict__ feat, const int* __restrict__ pg,
    const int* __restrict__ coords, const ushort* __restrict__ Wt,
    const float* __restrict__ bias, ushort* __restrict__ hf1_bf,
    float* __restrict__ statsAcc)
{
    const int l = threadIdx.x;
    const int r16 = l & 15, qd = l >> 4;
    const int bx = blockIdx.x, o = blockIdx.y;

    int p = bx * 64 + l;
    int pc = p < N_PTS ? p : N_PTS - 1;
    int px = coords[pc*4+1], py = coords[pc*4+2], pz = coords[pc*4+3];
    // corner base: e = o_bit - 1 + j_bit per axis
    int ex0 = px + ((o >> 2) & 1) - 1;
    int ey0 = py + ((o >> 1) & 1) - 1;
    int ez0 = pz + (o & 1) - 1;

    int rows8[8];
#pragma unroll
    for (int j = 0; j < 8; j++){
        int cx = ex0 + ((j >> 2) & 1), cy = ey0 + ((j >> 1) & 1), cz = ez0 + (j & 1);
        int row = N_PTS;
        if ((unsigned)cx < 32u && (unsigned)cy < 32u && (unsigned)cz < 32u){
            int pi = pg[cx * 1024 + cy * 32 + cz];
            if (pi >= 0) row = pi;
        }
        rows8[j] = row;
    }

    float4v acc[16];
#pragma unroll
    for (int c = 0; c < 16; c++) acc[c] = 0.f;

#pragma unroll
    for (int j = 0; j < 8; j++){
        int fr0 = __shfl(rows8[j],      r16, 64);
        int fr1 = __shfl(rows8[j], 16 + r16, 64);
        int fr2 = __shfl(rows8[j], 32 + r16, 64);
        int fr3 = __shfl(rows8[j], 48 + r16, 64);
        const ushort* a0 = feat + (size_t)fr0 * C_IN + qd * 8;
        const ushort* a1 = feat + (size_t)fr1 * C_IN + qd * 8;
        const ushort* a2 = feat + (size_t)fr2 * C_IN + qd * 8;
        const ushort* a3 = feat + (size_t)fr3 * C_IN + qd * 8;
        const ushort* wt = Wt + (size_t)(o * 8 + j) * 8192 + l * 8;
#pragma unroll
        for (int kb = 0; kb < 4; kb++){
            short8 b0 = *(const short8*)(wt + (kb*4+0)*512);
            short8 b1 = *(const short8*)(wt + (kb*4+1)*512);
            short8 b2 = *(const short8*)(wt + (kb*4+2)*512);
            short8 b3 = *(const short8*)(wt + (kb*4+3)*512);
            short8 av0 = *(const short8*)(a0 + kb*32);
            short8 av1 = *(const short8*)(a1 + kb*32);
            short8 av2 = *(const short8*)(a2 + kb*32);
            short8 av3 = *(const short8*)(a3 + kb*32);
            acc[0]  = __builtin_amdgcn_mfma_f32_16x16x32_bf16(av0, b0, acc[0],  0, 0, 0);
            acc[1]  = __builtin_amdgcn_mfma_f32_16x16x32_bf16(av0, b1, acc[1],  0, 0, 0);
            acc[2]  = __builtin_amdgcn_mfma_f32_16x16x32_bf16(av0, b2, acc[2],  0, 0, 0);
            acc[3]  = __builtin_amdgcn_mfma_f32_16x16x32_bf16(av0, b3, acc[3],  0, 0, 0);
            acc[4]  = __builtin_amdgcn_mfma_f32_16x16x32_bf16(av1, b0, acc[4],  0, 0, 0);
            acc[5]  = __builtin_amdgcn_mfma_f32_16x16x32_bf16(av1, b1, acc[5],  0, 0, 0);
            acc[6]  = __builtin_amdgcn_mfma_f32_16x16x32_bf16(av1, b2, acc[6],  0, 0, 0);
            acc[7]  = __builtin_amdgcn_mfma_f32_16x16x32_bf16(av1, b3, acc[7],  0, 0, 0);
            acc[8]  = __builtin_amdgcn_mfma_f32_16x16x32_bf16(av2, b0, acc[8],  0, 0, 0);
            acc[9]  = __builtin_amdgcn_mfma_f32_16x16x32_bf16(av2, b1, acc[9],  0, 0, 0);
            acc[10] = __builtin_amdgcn_mfma_f32_16x16x32_bf16(av2, b2, acc[10], 0, 0, 0);
            acc[11] = __builtin_amdgcn_mfma_f32_16x16x32_bf16(av2, b3, acc[11], 0, 0, 0);
            acc[12] = __builtin_amdgcn_mfma_f32_16x16x32_bf16(av3, b0, acc[12], 0, 0, 0);
            acc[13] = __builtin_amdgcn_mfma_f32_16x16x32_bf16(av3, b1, acc[13], 0, 0, 0);
            acc[14] = __builtin_amdgcn_mfma_f32_16x16x32_bf16(av3, b2, acc[14], 0, 0, 0);
            acc[15] = __builtin_amdgcn_mfma_f32_16x16x32_bf16(av3, b3, acc[15], 0, 0, 0);
        }
    }

    // epilogue: C/D layout col = lane&15, row = (lane>>4)*4 + reg; row-in-tile = parent
    float bsv[4] = { bias[r16], bias[16 + r16], bias[32 + r16], bias[48 + r16] };
    float ps[4] = {0,0,0,0}, pq[4] = {0,0,0,0};
#pragma unroll
    for (int rb = 0; rb < 4; rb++)
#pragma unroll
        for (int nb = 0; nb < 4; nb++)
#pragma unroll
            for (int rg = 0; rg < 4; rg++){
                int pr = bx * 64 + rb * 16 + qd * 4 + rg;
                float v = acc[rb * 4 + nb][rg] + bsv[nb];
                if (pr < N_PTS){
                    hf1_bf[(size_t)(o * N_PTS + pr) * 64 + nb * 16 + r16] = f2bf(v);
                    ps[nb] += v; pq[nb] += v * v;
                }
            }
#pragma unroll
    for (int nb = 0; nb < 4; nb++){
        float s1 = ps[nb], s2 = pq[nb];
        s1 += __shfl_xor(s1, 16, 64); s2 += __shfl_xor(s2, 16, 64);
        s1 += __shfl_xor(s1, 32, 64); s2 += __shfl_xor(s2, 32, 64);
        if (qd == 0){
            atomicAdd(&statsAcc[64 + nb * 16 + r16], s1);
            atomicAdd(&statsAcc[128 + nb * 16 + r16], s2);
        }
    }
}

// ================= conv2: corner-based implicit GEMM, octant-major h2 =================
// grid (313, 8). M-tile = 64 children (64 parents, fixed octant o), N=64, 27 taps K=64.
// h2 is octant-major [o'][p][64]: tap t's A row = o'(o,t)*N + pidx[j(o,t)] -- per tap
// the gathers land inside ONE 2.56MB octant-plane (fits an XCD L2); all blocks walk
// the same tap order -> convoy keeps the active plane cache-resident.
// Adds skip, writes fp32 out (child-major, as reference expects).
__global__ void __launch_bounds__(64, 3) conv2_corner(
    const ushort* __restrict__ feat, const int* __restrict__ pg,
    const int* __restrict__ coords, const ushort* __restrict__ Wt,
    const float* __restrict__ bias, const float* __restrict__ skip,
    float* __restrict__ out)
{
    const int l = threadIdx.x;
    const int r16 = l & 15, qd = l >> 4;
    const int bx = blockIdx.x, o = blockIdx.y;
    const int ox = (o >> 2) & 1, oy = (o >> 1) & 1, oz = o & 1;

    int p = bx * 64 + l;
    int pc = p < N_PTS ? p : N_PTS - 1;
    int px = coords[pc*4+1], py = coords[pc*4+2], pz = coords[pc*4+3];
    int ex0 = px + ox - 1, ey0 = py + oy - 1, ez0 = pz + oz - 1;

    int pb[8];   // parent index per corner, or N_PTS sentinel (invalid)
#pragma unroll
    for (int j = 0; j < 8; j++){
        int cx = ex0 + ((j >> 2) & 1), cy = ey0 + ((j >> 1) & 1), cz = ez0 + (j & 1);
        int pi_ = N_PTS;
        if ((unsigned)cx < 32u && (unsigned)cy < 32u && (unsigned)cz < 32u){
            int pi = pg[cx * 1024 + cy * 32 + cz];
            if (pi >= 0) pi_ = pi;
        }
        pb[j] = pi_;
    }

    float4v acc[16];
#pragma unroll
    for (int c = 0; c < 16; c++) acc[c] = 0.f;

#pragma unroll
    for (int t = 0; t < 27; t++){
        const int dx = t / 9 - 1, dy = (t / 3) % 3 - 1, dz = t % 3 - 1;
        int sx = ox + dx, sy = oy + dy, sz = oz + dz;
        int jx = (sx >> 1) - ox + 1, jy = (sy >> 1) - oy + 1, jz = (sz >> 1) - oz + 1;
        int opi = (sx & 1) * 4 + (sy & 1) * 2 + (sz & 1);   // block-uniform per tap
        // constant-index select tree (jx/jy/jz block-uniform 0/1)
        int m00 = jz ? pb[1] : pb[0];
        int m01 = jz ? pb[3] : pb[2];
        int m10 = jz ? pb[5] : pb[4];
        int m11 = jz ? pb[7] : pb[6];
        int n0 = jy ? m01 : m00;
        int n1 = jy ? m11 : m10;
        int sel = jx ? n1 : n0;
        // octant-major row: valid -> o'*N + pidx (inside one plane); invalid -> zero row 8N
        int row = (sel < N_PTS) ? (opi * N_PTS + sel) : (8 * N_PTS);
        int fr0 = __shfl(row,      r16, 64);
        int fr1 = __shfl(row, 16 + r16, 64);
        int fr2 = __shfl(row, 32 + r16, 64);
        int fr3 = __shfl(row, 48 + r16, 64);
        const ushort* a0 = feat + (size_t)fr0 * C_OUT + qd * 8;
        const ushort* a1 = feat + (size_t)fr1 * C_OUT + qd * 8;
        const ushort* a2 = feat + (size_t)fr2 * C_OUT + qd * 8;
        const ushort* a3 = feat + (size_t)fr3 * C_OUT + qd * 8;
        const ushort* wt = Wt + (size_t)t * 4096 + l * 8;
#pragma unroll
        for (int kb = 0; kb < 2; kb++){
            short8 b0 = *(const short8*)(wt + (kb*4+0)*512);
            short8 b1 = *(const short8*)(wt + (kb*4+1)*512);
            short8 b2 = *(const short8*)(wt + (kb*4+2)*512);
            short8 b3 = *(const short8*)(wt + (kb*4+3)*512);
            short8 av0 = *(const short8*)(a0 + kb*32);
            short8 av1 = *(const short8*)(a1 + kb*32);
            short8 av2 = *(const short8*)(a2 + kb*32);
            short8 av3 = *(const short8*)(a3 + kb*32);
            acc[0]  = __builtin_amdgcn_mfma_f32_16x16x32_bf16(av0, b0, acc[0],  0, 0, 0);
            acc[1]  = __builtin_amdgcn_mfma_f32_16x16x32_bf16(av0, b1, acc[1],  0, 0, 0);
            acc[2]  = __builtin_amdgcn_mfma_f32_16x16x32_bf16(av0, b2, acc[2],  0, 0, 0);
            acc[3]  = __builtin_amdgcn_mfma_f32_16x16x32_bf16(av0, b3, acc[3],  0, 0, 0);
            acc[4]  = __builtin_amdgcn_mfma_f32_16x16x32_bf16(av1, b0, acc[4],  0, 0, 0);
            acc[5]  = __builtin_amdgcn_mfma_f32_16x16x32_bf16(av1, b1, acc[5],  0, 0, 0);
            acc[6]  = __builtin_amdgcn_mfma_f32_16x16x32_bf16(av1, b2, acc[6],  0, 0, 0);
            acc[7]  = __builtin_amdgcn_mfma_f32_16x16x32_bf16(av1, b3, acc[7],  0, 0, 0);
            acc[8]  = __builtin_amdgcn_mfma_f32_16x16x32_bf16(av2, b0, acc[8],  0, 0, 0);
            acc[9]  = __builtin_amdgcn_mfma_f32_16x16x32_bf16(av2, b1, acc[9],  0, 0, 0);
            acc[10] = __builtin_amdgcn_mfma_f32_16x16x32_bf16(av2, b2, acc[10], 0, 0, 0);
            acc[11] = __builtin_amdgcn_mfma_f32_16x16x32_bf16(av2, b3, acc[11], 0, 0, 0);
            acc[12] = __builtin_amdgcn_mfma_f32_16x16x32_bf16(av3, b0, acc[12], 0, 0, 0);
            acc[13] = __builtin_amdgcn_mfma_f32_16x16x32_bf16(av3, b1, acc[13], 0, 0, 0);
            acc[14] = __builtin_amdgcn_mfma_f32_16x16x32_bf16(av3, b2, acc[14], 0, 0, 0);
            acc[15] = __builtin_amdgcn_mfma_f32_16x16x32_bf16(av3, b3, acc[15], 0, 0, 0);
        }
    }

    float bsv[4] = { bias[r16], bias[16 + r16], bias[32 + r16], bias[48 + r16] };
#pragma unroll
    for (int rb = 0; rb < 4; rb++)
#pragma unroll
        for (int rg = 0; rg < 4; rg++){
            int pr = bx * 64 + rb * 16 + qd * 4 + rg;
            if (pr < N_PTS){
                const float* sk = skip + (size_t)pr * 64;
#pragma unroll
                for (int nb = 0; nb < 4; nb++){
                    int co = nb * 16 + r16;
                    out[(size_t)(pr * 8 + o) * 64 + co] = acc[rb * 4 + nb][rg] + bsv[nb] + sk[co];
                }
            }
        }
}

// ================= K4: h2 = silu(gn2(hf1_bf16)) -> bf16 =================
// hf1 and h2 are both octant-major; per-row channel structure (64) unchanged,
// so the index arithmetic is identical to the child-major version.
__global__ void __launch_bounds__(256) h2_kernel(
    const ushort* __restrict__ hf1, const float* __restrict__ stats,
    const float* __restrict__ gg, const float* __restrict__ gb, ushort* __restrict__ h2)
{
    int i = (blockIdx.x * 256 + threadIdx.x) * 4;
    if (i >= M_PTS * C_OUT) return;
    int c0 = i & (C_OUT - 1);                    // multiple of 4
    const float inv = 1.0f / (M_PTS * 2.0f);
    float muA = (stats[64 + c0] + stats[64 + c0 + 1]) * inv;
    float vA  = (stats[128 + c0] + stats[128 + c0 + 1]) * inv - muA * muA;
    float rsA = rsqrtf(vA + EPS);
    float muB = (stats[64 + c0 + 2] + stats[64 + c0 + 3]) * inv;
    float vB  = (stats[128 + c0 + 2] + stats[128 + c0 + 3]) * inv - muB * muB;
    float rsB = rsqrtf(vB + EPS);
    ushort4 u = *(const ushort4*)(hf1 + i);
    ushort4 o;
    o.x = f2bf(silu((bf2f(u.x) - muA) * rsA * gg[c0+0] + gb[c0+0]));
    o.y = f2bf(silu((bf2f(u.y) - muA) * rsA * gg[c0+1] + gb[c0+1]));
    o.z = f2bf(silu((bf2f(u.z) - muB) * rsB * gg[c0+2] + gb[c0+2]));
    o.w = f2bf(silu((bf2f(u.w) - muB) * rsB * gg[c0+3] + gb[c0+3]));
    *(ushort4*)(h2 + i) = o;
}

extern "C" void kernel_launch(void* const* d_in, const int* in_sizes, int n_in,
                              void* d_out, int out_size, void* d_ws, size_t ws_size,
                              hipStream_t stream){
    const float* x   = (const float*)d_in[0];
    const int*   cds = (const int*)  d_in[1];
    const float* g1  = (const float*)d_in[2];
    const float* b1  = (const float*)d_in[3];
    const float* W1  = (const float*)d_in[4];
    const float* bb1 = (const float*)d_in[5];
    const float* g2  = (const float*)d_in[6];
    const float* b2  = (const float*)d_in[7];
    const float* W2  = (const float*)d_in[8];
    const float* bb2 = (const float*)d_in[9];
    const float* Wsk = (const float*)d_in[10];
    const float* bsk = (const float*)d_in[11];
    float* out = (float*)d_out;
    char* ws = (char*)d_ws;

    // workspace layout (16B-aligned); high-water 32,123,136 B (round-5-proven)
    float*  stats = (float*) (ws);                 // 192 f32 (zeroed via memsetAsync)
    int*    pg    = (int*)   (ws + 1024);          // 131072 B -> 132096
    ushort* h     = (ushort*)(ws + 132096);        // (N+1)*128 bf16 = 5,120,256 -> 5,252,352
    ushort* h2    = (ushort*)(ws + 5252352);       // (M+8)*64 bf16 = 20,481,024 -> 25,733,376
    float*  s     = (float*) (ws + 25733376);      // N*64 f32 = 5,120,000 -> 30,853,376
    ushort* Wt1   = (ushort*)(ws + 30853376);      // W1eff 64*8192*2 = 1,048,576 -> 31,901,952
    ushort* Wt2   = (ushort*)(ws + 31901952);      // 221,184 -> 32,123,136
    // hf1 (bf16, M*64, octant-major) lives in d_out between conv1 and h2_kernel;
    // conv2 overwrites d_out as f32 (child-major, reference layout).

    hipMemsetAsync(stats, 0, 192 * sizeof(float), stream);
    prep_kernel<<<3120, 256, 0, stream>>>(W1, W2, Wt1, Wt2, pg, h, h2, x, stats);
    mid_kernel<<<7579, 256, 0, stream>>>(cds, pg, x, stats, g1, b1, h, Wsk, bsk, s);
    conv1_corner<<<dim3(313, 8), 64, 0, stream>>>(h, pg, cds, Wt1, bb1,
                                                  (ushort*)d_out, stats);
    h2_kernel<<<12500, 256, 0, stream>>>((const ushort*)d_out, stats, g2, b2, h2);
    conv2_corner<<<dim3(313, 8), 64, 0, stream>>>(h2, pg, cds, Wt2, bb2, s, out);
}